// Round 13
// baseline (4555.643 us; speedup 1.0000x reference)
//
#include <hip/hip_runtime.h>
#include <stdint.h>

#define D 1024

typedef unsigned long long u64;
typedef unsigned int u32;

// ---------- monotonic float<->uint mapping for atomic max ----------
__device__ __forceinline__ u32 enc_f(float f) {
    u32 b = __float_as_uint(f);
    return (b & 0x80000000u) ? ~b : (b | 0x80000000u);
}
__device__ __forceinline__ float dec_f(u32 u) {
    u32 b = (u & 0x80000000u) ? (u ^ 0x80000000u) : ~u;
    return __uint_as_float(b);
}

// ---------- kernel A: max(X), max|X| ----------
__global__ void k_maxred(const float* __restrict__ X, u32* scal) {
    float mx = -INFINITY, ma = 0.f;
    int stride = gridDim.x * blockDim.x;
    for (int i = blockIdx.x * blockDim.x + threadIdx.x; i < D * D; i += stride) {
        float v = X[i];
        mx = fmaxf(mx, v);
        ma = fmaxf(ma, fabsf(v));
    }
    for (int o = 32; o; o >>= 1) {
        mx = fmaxf(mx, __shfl_xor(mx, o));
        ma = fmaxf(ma, __shfl_xor(ma, o));
    }
    if ((threadIdx.x & 63) == 0) {
        atomicMax(&scal[0], enc_f(mx));  // max_sim
        atomicMax(&scal[1], enc_f(ma));  // max|X|
    }
}

// ---------- kernel B: init dist (f32) and cross (f32) matrices ----------
__global__ void k_init(const float* __restrict__ X, const float* __restrict__ W,
                       float* __restrict__ dist, float* __restrict__ cross,
                       const u32* __restrict__ scal) {
    int idx = blockIdx.x * blockDim.x + threadIdx.x;
    if (idx >= D * D) return;
    float max_sim = dec_f(scal[0]);
    float MAXD = __fmul_rn(dec_f(scal[1]), 1000.0f);
    int i = idx >> 10, j = idx & (D - 1);
    float x = X[idx];
    // X is bitwise symmetric (0.5*(A+A^T)), so this matches max_sim - X[min][max]
    dist[idx] = (i == j) ? MAXD : __fsub_rn(max_sim, x);
    cross[idx] = (i == j) ? 0.0f : (W[idx] + W[j * D + i]);  // one addend is exactly 0
}

// ---------- kernel B2: initial per-row (min,argmin) over upper triangle ----------
__global__ void k_rowmin(const float* __restrict__ dist, float* __restrict__ values_g,
                         int* __restrict__ indices_g, const u32* __restrict__ scal) {
    int r = blockIdx.x;
    int lane = threadIdx.x;  // 64 threads = 1 wave
    float MAXD = __fmul_rn(dec_f(scal[1]), 1000.0f);
    u64 best = ((u64)__float_as_uint(MAXD) << 32);  // (MAXD, idx 0) like jnp.argmin on all-MAXD row
    const float* row = dist + (size_t)r * D;
    for (int j = lane; j < D; j += 64) {
        if (j > r) {
            u64 k = ((u64)__float_as_uint(row[j]) << 32) | (u32)j;
            if (k < best) best = k;
        }
    }
    for (int o = 32; o; o >>= 1) {
        u64 k2 = __shfl_xor(best, o);
        if (k2 < best) best = k2;
    }
    if (lane == 0) {
        values_g[r] = __uint_as_float((u32)(best >> 32));
        indices_g[r] = (int)(best & 0xffffffffu);
    }
}

// ---------- kernel C: persistent HAC loop — ONE barrier per iteration ----------
// Row state (value, argmin) in registers of owner thread; rescans by owning
// wave (intra-wave comms only); row-m1 min distributed via LDS atomicMin;
// cut by the m2-owning wave (shfl-relayed cross12); all phase-crossing scalars
// double/triple-buffered so every cross-wave dependency is barrier-separated.
__global__ void __launch_bounds__(1024) k_hac(
        float* __restrict__ dist, float* __restrict__ cross,
        const float* __restrict__ values_g, const int* __restrict__ indices_g,
        int* __restrict__ labels_g, const u32* __restrict__ scal) {
    __shared__ __align__(16) float newv_l[D];
    __shared__ float cs_l[D];
    __shared__ unsigned char dead_l[D];
    __shared__ int slot_l[D];
    __shared__ int label_l[D];
    __shared__ double within_l[D];
    __shared__ double energy_l[D];
    __shared__ u64 s_best3[3];  // global-argmin accumulators (3-buffered)
    __shared__ u64 rowm1_3[3];  // row-m1 min accumulators (3-buffered)
    __shared__ int s_take[2], s_pm1[2], s_plab[2], s_nm1[2];
    __shared__ float s_ncs[2];

    const int t = threadIdx.x;
    const int lane = t & 63, wid = t >> 6;
    const float MAXD = __fmul_rn(dec_f(scal[1]), 1000.0f);
    const u32 MAXDb = __float_as_uint(MAXD);

    float v = values_g[t];  // row-min value (register, owner = thread t)
    int ix = indices_g[t];  // row argmin col
    bool alive = true;

    cs_l[t] = 1.0f;
    dead_l[t] = 0;
    slot_l[t] = t;
    label_l[t] = t;
    within_l[t] = 0.0;
    energy_l[t] = 0.0;
    if (t == 0) {
        s_best3[0] = ~0ull; s_best3[1] = ~0ull; s_best3[2] = ~0ull;
        rowm1_3[0] = ~0ull; rowm1_3[1] = ~0ull; rowm1_3[2] = ~0ull;
        s_take[1] = 0; s_pm1[1] = -1; s_plab[1] = 0; s_nm1[1] = -1; s_ncs[1] = 0.f;
    }
    __syncthreads();
    // boot publish into s_best3[2] (read buffer of it=0)
    {
        u64 key = ((u64)__float_as_uint(v) << 32) | ((u32)t << 10) | (u32)ix;
        for (int o = 32; o; o >>= 1) {
            u64 k2 = __shfl_xor(key, o);
            if (k2 < key) key = k2;
        }
        if (lane == 0) atomicMin(&s_best3[2], key);
    }
    __syncthreads();

    for (int it = 0; it < D - 1; ++it) {
        const int rd3 = (it + 2) % 3, pub3 = it % 3, rst3 = (it + 1) % 3;
        const int RD = (it + 1) & 1, WR = it & 1;

        const u64 bk = s_best3[rd3];
        const int m1 = (int)((bk >> 10) & 1023);
        const int m2 = (int)(bk & 1023);
        const int pnm = s_nm1[RD];
        const float pnc = s_ncs[RD];
        const int ptake = s_take[RD], pm1 = s_pm1[RD], plab = s_plab[RD];
        const float cs1 = (m1 == pnm) ? pnc : cs_l[m1];
        const float cs2 = (m2 == pnm) ? pnc : cs_l[m2];
        const float ncs = __fadd_rn(cs1, cs2);

        // refresh row pm1 from last phase's distributed row-m1 min, then freeze m2
        if (t == pm1) {
            u64 rk = rowm1_3[rd3];
            v = __uint_as_float((u32)(rk >> 32));
            ix = (int)(rk & 1023);
        }
        if (t == m2) { alive = false; dead_l[t] = 1; v = MAXD; ix = 0; }

        // early rescan detection (registers only) + preload: overlaps d/c loads
        const bool early = alive && (v < MAXD) && (t != m1) && (ix == m2);
        const u64 eMask = __ballot(early);
        int candR = -1;
        float4 cr0, cr1, cr2, cr3;
        if (eMask) {
            candR = (wid << 6) + (__ffsll((unsigned long long)eMask) - 1);
            const float4* row4 = (const float4*)(dist + (size_t)candR * D);
            cr0 = row4[lane];
            cr1 = row4[lane + 64];
            cr2 = row4[lane + 128];
            cr3 = row4[lane + 192];
        }

        // main row loads
        float d1, d2, c1, c2;
        if (alive || t == m2) {
            d1 = dist[(size_t)m1 * D + t];
            d2 = dist[(size_t)m2 * D + t];
            c1 = cross[(size_t)m1 * D + t];
            c2 = cross[(size_t)m2 * D + t];
        }

        // bookkeeping in the load shadow
        if (t == 0) {
            if (pnm >= 0) cs_l[pnm] = pnc;  // commit pending cs (readers redirect)
            s_best3[rst3] = ~0ull;          // reset buffers published NEXT phase
            rowm1_3[rst3] = ~0ull;
        }
        {
            int sl = slot_l[t];
            if (ptake && sl == pm1) label_l[t] = plab;  // apply prev cut
            if (sl == m2) slot_l[t] = m1;               // merge membership
        }
        if (wid == (m2 >> 6) && lane == 0) {  // next-phase scalars (single writer)
            s_nm1[WR] = m1; s_ncs[WR] = ncs;
            s_pm1[WR] = m1; s_plab[WR] = D + it;
        }

        // merged values + stores
        float nv = MAXD, ncx = 0.0f;
        const bool do_st = alive && (t != m1);
        if (do_st) {
            nv = __fdiv_rn(__fadd_rn(__fmul_rn(d1, cs1), __fmul_rn(d2, cs2)), ncs);
            ncx = c1 + c2;
        }
        newv_l[t] = nv;  // MAXD for dead/m1/m2
        if (do_st) {
            dist[(size_t)m1 * D + t] = nv;
            dist[(size_t)t * D + m1] = nv;
            cross[(size_t)m1 * D + t] = ncx;
            cross[(size_t)t * D + m1] = ncx;
        }

        // cut decision (m2-owning wave; cross12 via shfl from thread m2)
        if (wid == (m2 >> 6)) {
            float cr12 = __shfl(c1, m2 & 63);
            if (lane == 0) {
                double merge_e = within_l[m1] + within_l[m2] + (double)cr12;
                double e_sum = energy_l[m1] + energy_l[m2];
                int take = (merge_e >= e_sum) ? 1 : 0;
                within_l[m1] = merge_e;
                energy_l[m1] = take ? merge_e : e_sum;
                s_take[WR] = take;
            }
        }

        // row-m1 min, distributed (every wave reduces its 64-col segment of nv)
        {
            u64 k = (t > m1) ? (((u64)__float_as_uint(nv) << 32) | ((u32)m1 << 10) | (u32)t)
                             : ~0ull;
            if (t == m1) k = ((u64)MAXDb << 32) | ((u32)m1 << 10);  // floor (MAXD, col 0)
            for (int o = 32; o; o >>= 1) {
                u64 k2 = __shfl_xor(k, o);
                if (k2 < k) k = k2;
            }
            if (lane == 0) {
                atomicMin(&s_best3[pub3], k);
                atomicMin(&rowm1_3[pub3], k);
            }
        }

        // incremental row-min maintenance (registers)
        bool late = false;
        if (alive && v < MAXD && t != m1) {
            if (ix == m2) {
                // early rescan path below refreshes v/ix
            } else if (ix == m1) {  // implies t < m1
                if (nv <= v) v = nv;  // argmin stays m1 (lowest-col tie preserved)
                else late = true;     // min rose -> rescan
            } else if (t < m1) {      // col m1 got nv in row t
                if (nv < v) { v = nv; ix = m1; }
                else if (nv == v && m1 < ix) ix = m1;  // jnp.argmin tie-break
            }
        }
        const u64 lMask = __ballot(late);

        // rescan: preloaded candidate (data already in flight since phase start)
        if (candR >= 0) {
            const float subst = newv_l[candR];  // same-wave LDS (lgkmcnt-ordered)
            u64 bb = ((u64)MAXDb << 32);        // (MAXD, col 0) floor
#pragma unroll
            for (int c = 0; c < 4; ++c) {
                float4 q4 = (c == 0) ? cr0 : (c == 1) ? cr1 : (c == 2) ? cr2 : cr3;
                int j0 = (lane + (c << 6)) << 2;
#pragma unroll
                for (int e = 0; e < 4; ++e) {
                    int j = j0 + e;
                    float dv = (e == 0) ? q4.x : (e == 1) ? q4.y : (e == 2) ? q4.z : q4.w;
                    if (j == m1) dv = subst;
                    if (j > candR && j != m2 && !dead_l[j]) {
                        u64 k = ((u64)__float_as_uint(dv) << 32) | (u32)j;
                        if (k < bb) bb = k;
                    }
                }
            }
            for (int o = 32; o; o >>= 1) {
                u64 k2 = __shfl_xor(bb, o);
                if (k2 < bb) bb = k2;
            }
            if (t == candR) { v = __uint_as_float((u32)(bb >> 32)); ix = (int)(bb & 1023); }
            if (lane == 0)
                atomicMin(&s_best3[pub3],
                          (bb & 0xffffffff00000000ull) | ((u32)candR << 10) | (bb & 1023));
        }
        // rescan: remaining early rows + late rows (fresh loads)
        {
            u64 todo = (eMask & ~((candR >= 0) ? (1ull << (candR & 63)) : 0ull)) | lMask;
            while (todo) {
                int l = __ffsll((unsigned long long)todo) - 1;
                todo &= todo - 1;
                const int r = (wid << 6) + l;
                const float subst = newv_l[r];
                u64 bb = ((u64)MAXDb << 32);
                const float4* row4 = (const float4*)(dist + (size_t)r * D);
#pragma unroll
                for (int c = 0; c < 4; ++c) {
                    float4 q4 = row4[lane + (c << 6)];
                    int j0 = (lane + (c << 6)) << 2;
#pragma unroll
                    for (int e = 0; e < 4; ++e) {
                        int j = j0 + e;
                        float dv = (e == 0) ? q4.x : (e == 1) ? q4.y : (e == 2) ? q4.z : q4.w;
                        if (j == m1) dv = subst;
                        if (j > r && j != m2 && !dead_l[j]) {
                            u64 k = ((u64)__float_as_uint(dv) << 32) | (u32)j;
                            if (k < bb) bb = k;
                        }
                    }
                }
                for (int o = 32; o; o >>= 1) {
                    u64 k2 = __shfl_xor(bb, o);
                    if (k2 < bb) bb = k2;
                }
                if (t == r) { v = __uint_as_float((u32)(bb >> 32)); ix = (int)(bb & 1023); }
                if (lane == 0)
                    atomicMin(&s_best3[pub3],
                              (bb & 0xffffffff00000000ull) | ((u32)r << 10) | (bb & 1023));
            }
        }

        // final publish: wave min over its 64 rows (stable + rescanned; m1 excluded)
        {
            u64 k = (t == m1) ? ~0ull
                              : (((u64)__float_as_uint(v) << 32) | ((u32)t << 10) | (u32)ix);
            for (int o = 32; o; o >>= 1) {
                u64 k2 = __shfl_xor(k, o);
                if (k2 < k) k = k2;
            }
            if (lane == 0) atomicMin(&s_best3[pub3], k);
        }
        __syncthreads();  // THE barrier: publishes LDS state + drains all vmem
    }

    // apply the final iteration's cut (written at it=D-2 into parity 0)
    {
        int lab = label_l[t];
        if (s_take[0] && slot_l[t] == s_pm1[0]) lab = s_plab[0];
        labels_g[t] = lab;
    }
}

// ---------- kernel D: R[a][b] = (a==b) || (label[a]==label[b]) ----------
__global__ void k_out(const int* __restrict__ labels, float* __restrict__ out) {
    int idx = blockIdx.x * blockDim.x + threadIdx.x;
    if (idx >= D * D) return;
    int i = idx >> 10, j = idx & (D - 1);
    out[idx] = (i == j || labels[i] == labels[j]) ? 1.0f : 0.0f;
}

extern "C" void kernel_launch(void* const* d_in, const int* in_sizes, int n_in,
                              void* d_out, int out_size, void* d_ws, size_t ws_size,
                              hipStream_t stream) {
    const float* X = (const float*)d_in[0];
    const float* W = (const float*)d_in[1];

    char* ws = (char*)d_ws;
    const size_t MAT_BYTES = (size_t)D * D * sizeof(float);  // 4 MiB each
    float* dist = (float*)ws;
    float* cross = (float*)(ws + MAT_BYTES);
    float* values_g = (float*)(ws + 2 * MAT_BYTES);
    int* indices_g = (int*)(ws + 2 * MAT_BYTES + 4096);
    int* labels_g = (int*)(ws + 2 * MAT_BYTES + 8192);
    u32* scal = (u32*)(ws + 2 * MAT_BYTES + 12288);

    hipMemsetAsync(scal, 0, 2 * sizeof(u32), stream);
    k_maxred<<<256, 256, 0, stream>>>(X, scal);
    k_init<<<(D * D) / 256, 256, 0, stream>>>(X, W, dist, cross, scal);
    k_rowmin<<<D, 64, 0, stream>>>(dist, values_g, indices_g, scal);
    k_hac<<<1, 1024, 0, stream>>>(dist, cross, values_g, indices_g, labels_g, scal);
    k_out<<<(D * D) / 256, 256, 0, stream>>>(labels_g, (float*)d_out);
}